// Round 6
// baseline (849.672 us; speedup 1.0000x reference)
//
#include <hip/hip_runtime.h>
#include <hip/hip_cooperative_groups.h>
#include <math.h>

namespace cg = cooperative_groups;

#define NB 512   // batch
#define NWAVE 2048  // 512 blocks * 4 waves

// ---------------- workspace layout (float offsets) ----------------
// T tables [r][co]: T1@0(2048) T2@2048(1024) T3@3072(288) T4@3360(256) T5@3616(16)
// WT [r][ci][co]:   WT1@4096(204800) WT2@208896(131072) WT3@339968(18432)
//                   WT4@358400(8192) WT5@366592(256)
// ACT region @366848 (1605632 max): xT then A1..A4 (layer overwrites, dead-safe)
// Y   region @1972480 (1605632 max): conv outputs [q][co][b]
// total 3,578,112 floats = 14.3 MB
#define OFF_T1 0
#define OFF_T2 2048
#define OFF_T3 3072
#define OFF_T4 3360
#define OFF_T5 3616
#define OFF_WT1 4096
#define OFF_WT2 208896
#define OFF_WT3 339968
#define OFF_WT4 358400
#define OFF_WT5 366592
#define OFF_ACT 366848
#define OFF_Y   1972480

// ---- vector load/store helpers (static-indexed, rule #20 safe) ----
__device__ __forceinline__ void loadv(float (&d)[1], const float* p){ d[0]=*p; }
__device__ __forceinline__ void loadv(float (&d)[2], const float* p){ float2 v=*reinterpret_cast<const float2*>(p); d[0]=v.x; d[1]=v.y; }
__device__ __forceinline__ void loadv(float (&d)[4], const float* p){ float4 v=*reinterpret_cast<const float4*>(p); d[0]=v.x; d[1]=v.y; d[2]=v.z; d[3]=v.w; }
__device__ __forceinline__ void storev(float* p, const float (&d)[1]){ *p=d[0]; }
__device__ __forceinline__ void storev(float* p, const float (&d)[2]){ *reinterpret_cast<float2*>(p)=make_float2(d[0],d[1]); }
__device__ __forceinline__ void storev(float* p, const float (&d)[4]){ *reinterpret_cast<float4*>(p)=make_float4(d[0],d[1],d[2],d[3]); }

// ---- stage 0: prep. WT[r][ci][co] transpose + xT[ci][b] + T[r][co] from raw w.
__device__ void prep_stage(const float* __restrict__ w1, const float* __restrict__ w2,
                           const float* __restrict__ w3, const float* __restrict__ w4,
                           const float* __restrict__ w5, const float* __restrict__ x,
                           float* __restrict__ ws, int gtid) {
  for (int idx = gtid; idx < 417584; idx += 131072) {
    if (idx < 362752) {
      const float* W; int CIN, COUT, KK, e, wtb;
      if (idx < 204800)      { W=w1; CIN=100; COUT=128; KK=16; e=idx;        wtb=OFF_WT1; }
      else if (idx < 335872) { W=w2; CIN=128; COUT=64;  KK=16; e=idx-204800; wtb=OFF_WT2; }
      else if (idx < 354304) { W=w3; CIN=64;  COUT=32;  KK=9;  e=idx-335872; wtb=OFF_WT3; }
      else if (idx < 362496) { W=w4; CIN=32;  COUT=16;  KK=16; e=idx-354304; wtb=OFF_WT4; }
      else                   { W=w5; CIN=16;  COUT=1;   KK=16; e=idx-362496; wtb=OFF_WT5; }
      int ci = e / (COUT*KK); int rem = e % (COUT*KK); int co = rem / KK; int r = rem % KK;
      ws[wtb + (r*CIN + ci)*COUT + co] = W[e];
    } else if (idx < 413952) {
      int j = idx - 362752;           // 51200: x transpose
      int b = j / 100, ci = j % 100;
      ws[OFF_ACT + ci*NB + b] = x[j];
    } else {
      int t = idx - 413952;           // 3632: T tables from raw w
      const float* W; int CIN, COUT, KK, tb, local;
      if (t < 2048)      { W=w1; CIN=100; COUT=128; KK=16; tb=OFF_T1; local=t; }
      else if (t < 3072) { W=w2; CIN=128; COUT=64;  KK=16; tb=OFF_T2; local=t-2048; }
      else if (t < 3360) { W=w3; CIN=64;  COUT=32;  KK=9;  tb=OFF_T3; local=t-3072; }
      else if (t < 3616) { W=w4; CIN=32;  COUT=16;  KK=16; tb=OFF_T4; local=t-3360; }
      else               { W=w5; CIN=16;  COUT=1;   KK=16; tb=OFF_T5; local=t-3616; }
      int r = local / COUT, co = local % COUT;
      float s = 0.f;
      #pragma unroll 4
      for (int ci = 0; ci < CIN; ++ci) s += fabsf(W[(ci*COUT + co)*KK + r]);
      ws[tb + local] = s;
    }
  }
}

// ---- conv stage: batch-on-lanes adder conv-transpose. wave per task.
// X: [p][ci][b]; W: [r][ci][co]; T: [r][co]; Y: [q][co][b]
template<int CIN,int COUT,int K,int PAD,int HI,int WI,int HO,int WO,int R_CO,int R_B>
__device__ void conv_stage(const float* __restrict__ X, const float* __restrict__ W,
                           const float* __restrict__ T, float* __restrict__ Y,
                           int gw, int lane) {
  constexpr int S = HO*WO, NCOG = COUT/R_CO, NBG = NB/(64*R_B), NT = S*NCOG*NBG;
  for (int task = gw; task < NT; task += NWAVE) {
    const int q   = task % S;
    const int t1  = task / S;
    const int cog = t1 % NCOG;
    const int bg  = t1 / NCOG;
    const int oh = q / WO, ow = q % WO;
    const int co0 = cog * R_CO;
    const int b0  = bg*(64*R_B) + lane * R_B;

    // structural-zero taps: |0 - w| summed via T table
    float init[R_CO];
    #pragma unroll
    for (int rc = 0; rc < R_CO; ++rc) init[rc] = 0.f;
    #pragma unroll
    for (int kh = 0; kh < K; ++kh) {
      #pragma unroll
      for (int kw = 0; kw < K; ++kw) {
        const int th = oh + PAD - kh, tw = ow + PAD - kw;
        const bool real = (th >= 0) && !(th & 1) && ((th >> 1) < HI)
                       && (tw >= 0) && !(tw & 1) && ((tw >> 1) < WI);
        if (!real) {
          const float* tp = T + (kh*K + kw)*COUT + co0;
          #pragma unroll
          for (int rc = 0; rc < R_CO; ++rc) init[rc] += tp[rc];
        }
      }
    }
    float acc[R_CO][R_B];
    #pragma unroll
    for (int rc = 0; rc < R_CO; ++rc)
      #pragma unroll
      for (int rb = 0; rb < R_B; ++rb) acc[rc][rb] = init[rc];

    // real taps: wave-uniform control, lanes carry b
    #pragma unroll
    for (int kh = 0; kh < K; ++kh) {
      const int th = oh + PAD - kh;
      if (th < 0 || (th & 1)) continue;
      const int ih = th >> 1;
      if (ih >= HI) continue;
      #pragma unroll
      for (int kw = 0; kw < K; ++kw) {
        const int tw = ow + PAD - kw;
        if (tw < 0 || (tw & 1)) continue;
        const int iw = tw >> 1;
        if (iw >= WI) continue;
        const int r = kh*K + kw, p = ih*WI + iw;
        const float* xp = X + (p*CIN)*NB + b0;
        const float* wp = W + (r*CIN)*COUT + co0;
        #pragma unroll 4
        for (int ci = 0; ci < CIN; ++ci) {
          float xv[R_B];
          loadv(xv, xp + ci*NB);
          #pragma unroll
          for (int rc = 0; rc < R_CO; ++rc) {
            const float wv = wp[ci*COUT + rc];   // wave-uniform -> scalar
            #pragma unroll
            for (int rb = 0; rb < R_B; ++rb)
              acc[rc][rb] += fabsf(xv[rb] - wv);
          }
        }
      }
    }
    float* yp = Y + (q*COUT + co0)*NB + b0;
    #pragma unroll
    for (int rc = 0; rc < R_CO; ++rc) storev(yp + rc*NB, acc[rc]);
  }
}

// ---- norm stage (layers 1-4): wave per (co,bg); lane-local over q; relu.
template<int COUT,int S>
__device__ void norm_stage(const float* __restrict__ Y, float* __restrict__ A,
                           int gw, int lane) {
  constexpr int NT = COUT * (NB/64);
  for (int task = gw; task < NT; task += NWAVE) {
    const int co = task % COUT;
    const int bg = task / COUT;
    const int b = bg*64 + lane;
    const float* yb = Y + co*NB + b;
    float s = 0.f;
    #pragma unroll 4
    for (int q = 0; q < S; ++q) s += yb[q*COUT*NB];
    const float mu = s * (1.f/S);
    float v = 0.f;
    #pragma unroll 4
    for (int q = 0; q < S; ++q) { const float d = yb[q*COUT*NB] - mu; v += d*d; }
    const float rs = rsqrtf(v * (1.f/S) + 1e-5f);
    #pragma unroll 4
    for (int q = 0; q < S; ++q) {
      const float n = (mu - yb[q*COUT*NB]) * rs;   // adder out = -y
      A[(q*COUT + co)*NB + b] = fmaxf(n, 0.f);
    }
  }
}

// ---- norm stage layer 5: COUT=1, S=784; wave per b; shuffle reduce; tanh -> out[b][q]
__device__ void norm5_stage(const float* __restrict__ Y, float* __restrict__ out,
                            int gw, int lane) {
  for (int b = gw; b < NB; b += NWAVE) {
    const float* yb = Y + b;
    float s = 0.f;
    for (int q = lane; q < 784; q += 64) s += yb[q*NB];
    #pragma unroll
    for (int off = 1; off < 64; off <<= 1) s += __shfl_xor(s, off, 64);
    const float mu = s * (1.f/784.f);
    float s2 = 0.f;
    for (int q = lane; q < 784; q += 64) { float d = yb[q*NB] - mu; s2 += d*d; }
    #pragma unroll
    for (int off = 1; off < 64; off <<= 1) s2 += __shfl_xor(s2, off, 64);
    const float rs = rsqrtf(s2*(1.f/784.f) + 1e-5f);
    for (int q = lane; q < 784; q += 64) {
      const float n = (mu - yb[q*NB]) * rs;
      const float ax = fabsf(n);
      const float e = __expf(-2.f*ax);
      const float t = (1.f - e) / (1.f + e);
      out[b*784 + q] = copysignf(t, n);   // tanh(n)
    }
  }
}

// ---- the whole net. stages [s_lo, s_hi]; grid.sync only when multiple stages
// (cooperative launch). Fallback path launches single stages (s_lo==s_hi).
__global__ __launch_bounds__(256, 2)
void fused(const float* __restrict__ x,
           const float* __restrict__ w1, const float* __restrict__ w2,
           const float* __restrict__ w3, const float* __restrict__ w4,
           const float* __restrict__ w5,
           float* __restrict__ ws, float* __restrict__ out,
           int s_lo, int s_hi) {
  const int gtid = blockIdx.x*256 + threadIdx.x;
  const int gw   = blockIdx.x*4 + (threadIdx.x >> 6);
  const int lane = threadIdx.x & 63;
  float* ACT = ws + OFF_ACT;
  float* Y   = ws + OFF_Y;
  cg::grid_group grid = cg::this_grid();

  for (int st = s_lo; st <= s_hi; ++st) {
    switch (st) {
      case 0: prep_stage(w1,w2,w3,w4,w5,x,ws,gtid); break;
      //                 CIN COUT K P  HI WI HO WO Rc Rb
      case 1: conv_stage<100,128,4,1,  1, 1, 2, 2, 4, 2>(ACT, ws+OFF_WT1, ws+OFF_T1, Y, gw, lane); break;
      case 2: norm_stage<128,  4>(Y, ACT, gw, lane); break;
      case 3: conv_stage<128, 64,4,1,  2, 2, 4, 4, 4, 2>(ACT, ws+OFF_WT2, ws+OFF_T2, Y, gw, lane); break;
      case 4: norm_stage< 64, 16>(Y, ACT, gw, lane); break;
      case 5: conv_stage< 64, 32,3,1,  4, 4, 7, 7, 4, 2>(ACT, ws+OFF_WT3, ws+OFF_T3, Y, gw, lane); break;
      case 6: norm_stage< 32, 49>(Y, ACT, gw, lane); break;
      case 7: conv_stage< 32, 16,4,1,  7, 7,14,14, 4, 2>(ACT, ws+OFF_WT4, ws+OFF_T4, Y, gw, lane); break;
      case 8: norm_stage< 16,196>(Y, ACT, gw, lane); break;
      case 9: conv_stage< 16,  1,4,1, 14,14,28,28, 1, 4>(ACT, ws+OFF_WT5, ws+OFF_T5, Y, gw, lane); break;
      case 10: norm5_stage(Y, out, gw, lane); break;
    }
    if (st < s_hi) grid.sync();
  }
}

extern "C" void kernel_launch(void* const* d_in, const int* in_sizes, int n_in,
                              void* d_out, int out_size, void* d_ws, size_t ws_size,
                              hipStream_t stream) {
  const float* x  = (const float*)d_in[0];
  const float* w1 = (const float*)d_in[1];
  const float* w2 = (const float*)d_in[2];
  const float* w3 = (const float*)d_in[3];
  const float* w4 = (const float*)d_in[4];
  const float* w5 = (const float*)d_in[5];
  float* ws  = (float*)d_ws;
  float* out = (float*)d_out;

  int s_lo = 0, s_hi = 10;
  void* args[] = {(void*)&x, (void*)&w1, (void*)&w2, (void*)&w3, (void*)&w4,
                  (void*)&w5, (void*)&ws, (void*)&out, (void*)&s_lo, (void*)&s_hi};
  hipError_t e = hipLaunchCooperativeKernel((const void*)fused, dim3(512), dim3(256),
                                            args, 0, stream);
  if (e != hipSuccess) {
    // graceful degradation: one launch per stage (kernel boundaries = sync)
    for (int st = 0; st <= 10; ++st)
      fused<<<512, 256, 0, stream>>>(x, w1, w2, w3, w4, w5, ws, out, st, st);
  }
}

// Round 8
// 320.191 us; speedup vs baseline: 2.6536x; 2.6536x over previous
//
#include <hip/hip_runtime.h>
#include <math.h>

// ---------------- workspace layout (float offsets) ----------------
// T tables [r][co]: T1@0(2048) T2@2048(1024) T3@3072(288) T4@3360(256) T5@3616(16)
// S tables [co]:    S1@3632(128) S2@3760(64) S3@3824(32) S4@3856(16) S5@3872(1)
// WT [r][ci4][co][4]: WT1@4096(204800) WT2@208896(131072) WT3@339968(18432)
//                     WT4@358400(8192) WT5@366592(256)  total 366848 floats
#define OFF_T1 0
#define OFF_T2 2048
#define OFF_T3 3072
#define OFF_T4 3360
#define OFF_T5 3616
#define OFF_S1 3632
#define OFF_S2 3760
#define OFF_S3 3824
#define OFF_S4 3856
#define OFF_S5 3872
#define OFF_WT1 4096
#define OFF_WT2 208896
#define OFF_WT3 339968
#define OFF_WT4 358400
#define OFF_WT5 366592

// prep: (a) weights -> WT[r][ci4][co][4], (b) T[r][co] = sum_ci |w|,
//       (c) Ssum[co] = sum_{ci,r} |w|  -- all from raw w, no dependencies.
__global__ __launch_bounds__(256)
void prep(const float* __restrict__ w1, const float* __restrict__ w2,
          const float* __restrict__ w3, const float* __restrict__ w4,
          const float* __restrict__ w5, float* __restrict__ ws) {
  int idx = blockIdx.x * 256 + threadIdx.x;
  if (idx < 362752) {
    const float* W; int CIN, COUT, KK, e, wtb;
    if (idx < 204800)      { W=w1; CIN=100; COUT=128; KK=16; e=idx;        wtb=OFF_WT1; }
    else if (idx < 335872) { W=w2; CIN=128; COUT=64;  KK=16; e=idx-204800; wtb=OFF_WT2; }
    else if (idx < 354304) { W=w3; CIN=64;  COUT=32;  KK=9;  e=idx-335872; wtb=OFF_WT3; }
    else if (idx < 362496) { W=w4; CIN=32;  COUT=16;  KK=16; e=idx-354304; wtb=OFF_WT4; }
    else                   { W=w5; CIN=16;  COUT=1;   KK=16; e=idx-362496; wtb=OFF_WT5; }
    int ci = e / (COUT*KK); int rem = e % (COUT*KK); int co = rem / KK; int r = rem % KK;
    ws[wtb + ((r*(CIN/4) + (ci>>2))*COUT + co)*4 + (ci&3)] = W[e];
  } else if (idx < 366384) {
    int t = idx - 362752;           // 3632: T tables from raw w
    const float* W; int CIN, COUT, KK, tb, local;
    if (t < 2048)      { W=w1; CIN=100; COUT=128; KK=16; tb=OFF_T1; local=t; }
    else if (t < 3072) { W=w2; CIN=128; COUT=64;  KK=16; tb=OFF_T2; local=t-2048; }
    else if (t < 3360) { W=w3; CIN=64;  COUT=32;  KK=9;  tb=OFF_T3; local=t-3072; }
    else if (t < 3616) { W=w4; CIN=32;  COUT=16;  KK=16; tb=OFF_T4; local=t-3360; }
    else               { W=w5; CIN=16;  COUT=1;   KK=16; tb=OFF_T5; local=t-3616; }
    int r = local / COUT, co = local % COUT;
    float s = 0.f;
    #pragma unroll 4
    for (int ci = 0; ci < CIN; ++ci) s += fabsf(W[(ci*COUT + co)*KK + r]);
    ws[tb + local] = s;
  } else if (idx < 366625) {
    int t = idx - 366384;           // 241: Ssum tables from raw w
    const float* W; int CIN, COUT, KK, sb, co;
    if (t < 128)       { W=w1; CIN=100; COUT=128; KK=16; sb=OFF_S1; co=t; }
    else if (t < 192)  { W=w2; CIN=128; COUT=64;  KK=16; sb=OFF_S2; co=t-128; }
    else if (t < 224)  { W=w3; CIN=64;  COUT=32;  KK=9;  sb=OFF_S3; co=t-192; }
    else if (t < 240)  { W=w4; CIN=32;  COUT=16;  KK=16; sb=OFF_S4; co=t-224; }
    else               { W=w5; CIN=16;  COUT=1;   KK=16; sb=OFF_S5; co=t-240; }
    float s = 0.f;
    for (int ci = 0; ci < CIN; ++ci) {
      const float* wp = W + (ci*COUT + co)*KK;
      #pragma unroll 4
      for (int r = 0; r < KK; ++r) s += fabsf(wp[r]);
    }
    ws[sb + co] = s;
  }
}

// ---- generic adder conv-transpose stage (stride 2, pad 1), block-local.
// X (LDS): [ci4][p*2+b][4]   Y (LDS): [co*2+b][q]   WT (global): [r][ci4][co][4]
// Lane owns an aligned 2x2 output tile: for each (kh,kw) exactly one quadrant
// matches the stride-2 parity -> wave-uniform tap loop, no divergence.
// acc starts at Ssum[co] (all K*K taps as structural |w|); each parity-matching
// in-bounds tap corrects by (tap - T[r]):  total = Σ_all T + Σ_real (tap - T).
template<int CIN,int COUT,int K,int HI,int WI,int HO,int WO,int T_L,int CO_LANE,int B_L>
__device__ __forceinline__ void conv(const float* __restrict__ X, float* __restrict__ Y,
                                     const float* __restrict__ WT, const float* __restrict__ Tt,
                                     const float* __restrict__ Ss,
                                     int wave, int lane) {
  constexpr int CIN4 = CIN/4, S = HO*WO, THT = (HO+1)/2, TWT = (WO+1)/2;
  constexpr int NTILES = THT*TWT;
  constexpr int NTG = (NTILES + T_L - 1)/T_L, NCOG = COUT/CO_LANE, NBT = 2/B_L;
  constexpr int NT = NTG*NCOG*NBT;
  const int tl = lane / (CO_LANE*B_L);
  const int lc = (lane / B_L) % CO_LANE;
  const int lb = lane % B_L;
  for (int t = wave; t < NT; t += 8) {
    const int tg  = t % NTG;
    const int r1  = t / NTG;
    const int cog = r1 % NCOG;
    const int tb  = r1 / NCOG;
    const int b   = (B_L == 2) ? lb : tb;
    const int co  = cog*CO_LANE + lc;
    const int tile = tg*T_L + tl;
    const bool tval = (tile < NTILES);
    const int tc  = tval ? tile : 0;
    const int th_ = tc / TWT, tw_ = tc % TWT;

    const float base = Ss[co];
    float acc[4] = {base, base, base, base};   // quadrant (dh*2+dw), static-indexed
    #pragma unroll
    for (int kh = 0; kh < K; ++kh) {
      const int dh = (kh+1)&1;
      const int c1 = (dh + 1 - kh) >> 1;          // PAD=1: ih = th_ + c1 (exact, even)
      const int ih = th_ + c1, oh = 2*th_ + dh;
      const bool vh = (ih >= 0) && (ih < HI) && (oh < HO);
      const int ihc = min(max(ih, 0), HI-1);
      #pragma unroll
      for (int kw = 0; kw < K; ++kw) {
        const int dw = (kw+1)&1;
        const int c2 = (dw + 1 - kw) >> 1;
        const int iw = tw_ + c2, ow = 2*tw_ + dw;
        const bool vw = (iw >= 0) && (iw < WI) && (ow < WO);
        const int iwc = min(max(iw, 0), WI-1);
        const float maskf = (vh && vw && tval) ? 1.f : 0.f;
        const int r = kh*K + kw;
        const float Tv = Tt[r*COUT + co];
        const int pb = (ihc*WI + iwc)*2 + b;
        const float4* xp = reinterpret_cast<const float4*>(X) + pb;
        const float4* wp = reinterpret_cast<const float4*>(WT) + (size_t)r*CIN4*COUT + co;
        float tap = 0.f;
        #pragma unroll 4
        for (int c = 0; c < CIN4; ++c) {
          const float4 xv = xp[c*(2*HI*WI)];
          const float4 wv = wp[c*COUT];
          tap += fabsf(xv.x - wv.x) + fabsf(xv.y - wv.y)
               + fabsf(xv.z - wv.z) + fabsf(xv.w - wv.w);
        }
        acc[dh*2+dw] += maskf*(tap - Tv);
      }
    }
    #pragma unroll
    for (int dh = 0; dh < 2; ++dh) {
      #pragma unroll
      for (int dw = 0; dw < 2; ++dw) {
        const int oh = 2*th_ + dh, ow = 2*tw_ + dw;
        if (tval && oh < HO && ow < WO)
          Y[(co*2 + b)*S + oh*WO + ow] = acc[dh*2+dw];
      }
    }
  }
}

// ---- instance norm + relu (layers 1-4), block-local.
// Y: [ch][S] (ch = co*2+b); writes next conv input layout [co4][q*2+b][4].
template<int COUT,int S>
__device__ __forceinline__ void norm(const float* __restrict__ Y, float* __restrict__ Xn, int tid) {
  constexpr int NCH = COUT*2, PT = 512/NCH;   // PT in {2,4,8,16}, divides 64
  const int ch = tid / PT, j = tid % PT;
  const int co = ch >> 1, b = ch & 1;
  const float* yp = Y + ch*S;
  float s = 0.f;
  for (int q = j; q < S; q += PT) s += yp[q];
  #pragma unroll
  for (int off = 1; off < PT; off <<= 1) s += __shfl_xor(s, off, 64);
  const float mu = s * (1.f/S);
  float v = 0.f;
  for (int q = j; q < S; q += PT) { const float d = yp[q] - mu; v += d*d; }
  #pragma unroll
  for (int off = 1; off < PT; off <<= 1) v += __shfl_xor(v, off, 64);
  const float rs = rsqrtf(v * (1.f/S) + 1e-5f);
  for (int q = j; q < S; q += PT) {
    float n = (mu - yp[q]) * rs;            // adder out = -y, norm flips sign
    n = fmaxf(n, 0.f);
    Xn[(((co>>2)*S + q)*2 + b)*4 + (co&3)] = n;
  }
}

// ---- final norm: COUT=1, S=784, tanh, write global out[b][q]
__device__ __forceinline__ void norm5(const float* __restrict__ Y, float* __restrict__ out,
                                      int tid, int blk, float* __restrict__ scratch) {
  const int b = tid >> 8, j = tid & 255;
  const int wid = tid >> 6, lane = tid & 63;
  const float* yp = Y + b*784;
  float s = 0.f;
  for (int q = j; q < 784; q += 256) s += yp[q];
  #pragma unroll
  for (int off = 1; off < 64; off <<= 1) s += __shfl_xor(s, off, 64);
  if (lane == 0) scratch[wid] = s;
  __syncthreads();
  const float mu = (scratch[b*4] + scratch[b*4+1] + scratch[b*4+2] + scratch[b*4+3]) * (1.f/784.f);
  __syncthreads();
  float v = 0.f;
  for (int q = j; q < 784; q += 256) { const float d = yp[q] - mu; v += d*d; }
  #pragma unroll
  for (int off = 1; off < 64; off <<= 1) v += __shfl_xor(v, off, 64);
  if (lane == 0) scratch[wid] = v;
  __syncthreads();
  const float rs = rsqrtf((scratch[b*4] + scratch[b*4+1] + scratch[b*4+2] + scratch[b*4+3]) * (1.f/784.f) + 1e-5f);
  for (int q = j; q < 784; q += 256) {
    const float n = (mu - yp[q]) * rs;
    const float ax = fabsf(n);
    const float e = __expf(-2.f*ax);
    out[(2*blk + b)*784 + q] = copysignf((1.f - e)/(1.f + e), n);
  }
}

// ---- whole net per b-pair, all activations in LDS, block-local syncs only.
__global__ __launch_bounds__(512, 1)
void fused_main(const float* __restrict__ x, const float* __restrict__ ws,
                float* __restrict__ out) {
  __shared__ float P[6272];      // activation arena (conv inputs)
  __shared__ float Q[6272];      // conv-output arena
  __shared__ float scratch[8];
  const int tid = threadIdx.x;
  const int wave = tid >> 6, lane = tid & 63;
  const int blk = blockIdx.x;

  // load x[2 rows of 100] into L1-input layout [ci4][b][4]
  for (int t = tid; t < 200; t += 512) {
    const int b = t / 100, ci = t % 100;
    P[((ci>>2)*2 + b)*4 + (ci&3)] = x[(2*blk + b)*100 + ci];
  }
  __syncthreads();
  //   CIN COUT K HI WI HO WO  T_L CO_LANE B_L
  conv<100,128,4, 1, 1, 2, 2,   1, 32, 2>(P, Q, ws+OFF_WT1, ws+OFF_T1, ws+OFF_S1, wave, lane);
  __syncthreads();
  norm<128, 4>(Q, P, tid);
  __syncthreads();
  conv<128, 64,4, 2, 2, 4, 4,   4, 16, 1>(P, Q, ws+OFF_WT2, ws+OFF_T2, ws+OFF_S2, wave, lane);
  __syncthreads();
  norm<64, 16>(Q, P, tid);
  __syncthreads();
  conv< 64, 32,3, 4, 4, 7, 7,  16,  4, 1>(P, Q, ws+OFF_WT3, ws+OFF_T3, ws+OFF_S3, wave, lane);
  __syncthreads();
  norm<32, 49>(Q, P, tid);
  __syncthreads();
  conv< 32, 16,4, 7, 7,14,14,  16,  4, 1>(P, Q, ws+OFF_WT4, ws+OFF_T4, ws+OFF_S4, wave, lane);
  __syncthreads();
  norm<16, 196>(Q, P, tid);
  __syncthreads();
  conv< 16,  1,4,14,14,28,28,  32,  1, 2>(P, Q, ws+OFF_WT5, ws+OFF_T5, ws+OFF_S5, wave, lane);
  __syncthreads();
  norm5(Q, out, tid, blk, scratch);
}

extern "C" void kernel_launch(void* const* d_in, const int* in_sizes, int n_in,
                              void* d_out, int out_size, void* d_ws, size_t ws_size,
                              hipStream_t stream) {
  const float* x  = (const float*)d_in[0];
  const float* w1 = (const float*)d_in[1];
  const float* w2 = (const float*)d_in[2];
  const float* w3 = (const float*)d_in[3];
  const float* w4 = (const float*)d_in[4];
  const float* w5 = (const float*)d_in[5];
  float* ws  = (float*)d_ws;
  float* out = (float*)d_out;

  prep<<<1433, 256, 0, stream>>>(w1, w2, w3, w4, w5, ws);
  fused_main<<<256, 512, 0, stream>>>(x, ws, out);
}